// Round 1
// baseline (5939.227 us; speedup 1.0000x reference)
//
#include <hip/hip_runtime.h>
#include <math.h>

// ---------------- problem constants ----------------
#define BATCH   16
#define DMODEL  512
#define EKEY    128
#define HWSZ    484
#define LENC    1452                       // 3*484
#define IMG_ELEMS (HWSZ*BATCH*DMODEL)      // 3,964,928 floats per image [484][16][512]
#define ENC_OUT   11894784ull              // 3*16*512*484 (enc_feat flat size)
#define SQRT_TEMP 5.4772255750516611f      // sqrt(30); folded into BOTH normalized projections
#define INORM_SCALE 0.011048543456039806f  // sqrt(1/(512*16))

__device__ __forceinline__ float inorm_coef(float ss) {
  // InstanceL2Norm: SCALE * sqrt(d*h*w / (ss + eps)), d*h*w = 512*484 = 247808
  return INORM_SCALE * sqrtf(247808.0f / (ss + 1e-5f));
}

// ---------------- tiny init ----------------
__global__ void init_zero_kernel(float* __restrict__ ss) { ss[threadIdx.x] = 0.0f; }

// ---------------- sinusoidal position embedding: pe[p][c], p<484, c<512 ----------------
__global__ void pe_kernel(float* __restrict__ pe) {
  const int p = blockIdx.x;
  const int j = threadIdx.x;                 // 0..255
  const float expo = (float)(2 * j) * (1.0f / 512.0f);
  const float invf = 1.0f / powf(10000.0f, expo);
  const float ang  = (float)(p + 1) * invf;
  pe[p * 512 + j]       = sinf(ang);
  pe[p * 512 + 256 + j] = cosf(ang);
}

// label[(i,b,p)] -> labelf[(i*484+p)*16 + b]
__global__ void build_label_kernel(const float* __restrict__ lab, float* __restrict__ labelf) {
  const int g = blockIdx.x;                  // img*16+b, img<3
  const int im = g >> 4, b = g & 15;
  for (int p = threadIdx.x; p < HWSZ; p += blockDim.x)
    labelf[((size_t)im * HWSZ + p) * BATCH + b] = lab[((size_t)im * BATCH + b) * HWSZ + p];
}

// ---------------- feat[(i,b,c,p)] + 1e-3*pe[p][c] -> dst[(i*484+p)][b][c] (tile transpose) ----------------
__global__ __launch_bounds__(256) void build_input_kernel(
    const float* __restrict__ trainf, const float* __restrict__ testf,
    const float* __restrict__ pe, int i0, float* __restrict__ dst)
{
  __shared__ float tile[32][33];
  const int tx = threadIdx.x, ty = threadIdx.y;   // 32 x 8
  const int pt = blockIdx.x * 32, ct = blockIdx.y * 32;
  const int im = blockIdx.z >> 4, b = blockIdx.z & 15;
  const int g = i0 + im;                           // global image 0..5
  const float* src = (g < 3 ? trainf + (size_t)g * IMG_ELEMS
                            : testf + (size_t)(g - 3) * IMG_ELEMS)
                     + (size_t)b * (512 * 484);
#pragma unroll
  for (int j = 0; j < 4; ++j) {
    const int c = ct + ty + 8 * j, p = pt + tx;
    tile[ty + 8 * j][tx] = (p < HWSZ) ? src[(size_t)c * 484 + p] : 0.0f; // tile[c_loc][p_loc]
  }
  __syncthreads();
#pragma unroll
  for (int j = 0; j < 4; ++j) {
    const int p = pt + ty + 8 * j, c = ct + tx;
    if (p < HWSZ)
      dst[(((size_t)im * HWSZ + p) * BATCH + b) * DMODEL + c] =
          tile[tx][ty + 8 * j] + 1e-3f * pe[p * 512 + c];
  }
}

// ---------------- projection + L2-normalize + sqrt(30) fold ----------------
// X: [M][512] rows=(l*16+b); W: [128][512]; PT out per image: [16][128][L] (transposed for score loop)
__global__ __launch_bounds__(256) void proj_kernel(
    const float* __restrict__ X, const float* __restrict__ W,
    const float* __restrict__ bias, float* __restrict__ PT, int L)
{
  __shared__ float Xs[32][64];    // [kk][m]
  __shared__ float Ws[32][128];   // [kk][e]
  const int t = threadIdx.x;
  const int row0 = blockIdx.x * 64;
  const int tx = t & 15, ty = t >> 4;
  float acc[4][8];
#pragma unroll
  for (int r = 0; r < 4; ++r)
#pragma unroll
    for (int j = 0; j < 8; ++j) acc[r][j] = 0.0f;

  for (int k0 = 0; k0 < 512; k0 += 32) {
    {
      const int m = t >> 2, kof = (t & 3) * 8;
      const float* xp = X + (size_t)(row0 + m) * 512 + k0 + kof;
      const float4 a0 = *(const float4*)xp;
      const float4 a1 = *(const float4*)(xp + 4);
      Xs[kof + 0][m] = a0.x; Xs[kof + 1][m] = a0.y; Xs[kof + 2][m] = a0.z; Xs[kof + 3][m] = a0.w;
      Xs[kof + 4][m] = a1.x; Xs[kof + 5][m] = a1.y; Xs[kof + 6][m] = a1.z; Xs[kof + 7][m] = a1.w;
    }
    {
      const int e = t >> 1, kof = (t & 1) * 16;
      const float* wp = W + (size_t)e * 512 + k0 + kof;
#pragma unroll
      for (int j = 0; j < 4; ++j) {
        const float4 w4 = *(const float4*)(wp + 4 * j);
        Ws[kof + 4 * j + 0][e] = w4.x; Ws[kof + 4 * j + 1][e] = w4.y;
        Ws[kof + 4 * j + 2][e] = w4.z; Ws[kof + 4 * j + 3][e] = w4.w;
      }
    }
    __syncthreads();
#pragma unroll
    for (int kk = 0; kk < 32; ++kk) {
      const float4 a  = *(const float4*)&Xs[kk][ty * 4];
      const float4 b0 = *(const float4*)&Ws[kk][tx * 8];
      const float4 b1 = *(const float4*)&Ws[kk][tx * 8 + 4];
      const float ar[4] = {a.x, a.y, a.z, a.w};
      const float br[8] = {b0.x, b0.y, b0.z, b0.w, b1.x, b1.y, b1.z, b1.w};
#pragma unroll
      for (int r = 0; r < 4; ++r)
#pragma unroll
        for (int j = 0; j < 8; ++j) acc[r][j] = fmaf(ar[r], br[j], acc[r][j]);
    }
    __syncthreads();
  }

  float bj[8];
#pragma unroll
  for (int j = 0; j < 8; ++j) bj[j] = bias[tx * 8 + j];

#pragma unroll
  for (int r = 0; r < 4; ++r) {
    float y[8];
    float ssq = 0.0f;
#pragma unroll
    for (int j = 0; j < 8; ++j) { y[j] = acc[r][j] + bj[j]; ssq = fmaf(y[j], y[j], ssq); }
    ssq += __shfl_xor(ssq, 1, 16);
    ssq += __shfl_xor(ssq, 2, 16);
    ssq += __shfl_xor(ssq, 4, 16);
    ssq += __shfl_xor(ssq, 8, 16);
    const float inv = SQRT_TEMP / fmaxf(sqrtf(ssq), 1e-12f);
    const int row = row0 + ty * 4 + r;
    const int lg = row >> 4, b = row & 15;
    const int im = lg / L, ll = lg - im * L;
    float* pp = PT + (((size_t)im * BATCH + b) * EKEY) * (size_t)L + ll;
#pragma unroll
    for (int j = 0; j < 8; ++j) pp[(size_t)(tx * 8 + j) * L] = y[j] * inv;
  }
}

// ---------------- fused attention (two-pass flash softmax) ----------------
__device__ __forceinline__ void compute_scores(
    const float pq_s[16][132], const float* __restrict__ pkb, int kc, int Lk, float s[16])
{
#pragma unroll
  for (int qi = 0; qi < 16; ++qi) s[qi] = 0.0f;
  const float* pkp = pkb + kc;
#pragma unroll 2
  for (int e = 0; e < 128; e += 4) {
    const float kv0 = pkp[(size_t)(e + 0) * Lk];
    const float kv1 = pkp[(size_t)(e + 1) * Lk];
    const float kv2 = pkp[(size_t)(e + 2) * Lk];
    const float kv3 = pkp[(size_t)(e + 3) * Lk];
#pragma unroll
    for (int qi = 0; qi < 16; ++qi) {
      const float4 pq4 = *(const float4*)&pq_s[qi][e];
      float sv = s[qi];
      sv = fmaf(pq4.x, kv0, sv); sv = fmaf(pq4.y, kv1, sv);
      sv = fmaf(pq4.z, kv2, sv); sv = fmaf(pq4.w, kv3, sv);
      s[qi] = sv;
    }
  }
}

// pqT/pkT: [B][128][L] (pre-normalized, *sqrt(30)); V: [Lk][B][512]; O: [Lq][B][512]
// kscale (label, [Lk][B]) folds the per-key value scale; maskOut gets sum_k p*kscale.
__global__ __launch_bounds__(256) void attn_kernel(
    const float* __restrict__ pqT, const float* __restrict__ pkT,
    const float* __restrict__ V, const float* __restrict__ kscale,
    float* __restrict__ O, float* __restrict__ maskOut,
    int Lq, int Lk,
    size_t pq_is, size_t pk_is, size_t v_is, size_t o_is, size_t mo_is)
{
  __shared__ float pq_s[16][132];
  __shared__ float S[16][256];
  __shared__ float m_sh[16], l_sh[16], linv_sh[16];

  const int t = threadIdx.x;
  const int b = blockIdx.y;
  const int im = blockIdx.z;
  const int q0 = blockIdx.x * 16;

  pqT += (size_t)im * pq_is;
  pkT += (size_t)im * pk_is;
  V   += (size_t)im * v_is;
  O   += (size_t)im * o_is;
  if (maskOut) maskOut += (size_t)im * mo_is;

  for (int idx = t; idx < 16 * 128; idx += 256) {
    const int e = idx >> 4, qi = idx & 15;
    const int q = q0 + qi;
    pq_s[qi][e] = (q < Lq) ? pqT[((size_t)b * 128 + e) * (size_t)Lq + q] : 0.0f;
  }
  if (t < 16) { m_sh[t] = -__builtin_inff(); l_sh[t] = 0.0f; }
  __syncthreads();

  const int nchunk = (Lk + 255) >> 8;
  const float* pkb = pkT + (size_t)b * 128 * (size_t)Lk;

  // ---- pass 1: online max / sumexp ----
  for (int ch = 0; ch < nchunk; ++ch) {
    const int k = ch * 256 + t;
    const bool kin = (k < Lk);
    const int kc = kin ? k : (Lk - 1);
    float s[16];
    compute_scores(pq_s, pkb, kc, Lk, s);
#pragma unroll
    for (int qi = 0; qi < 16; ++qi) S[qi][t] = kin ? s[qi] : -__builtin_inff();
    __syncthreads();
    {
      const int wv = t >> 6, lane = t & 63;
#pragma unroll
      for (int rep = 0; rep < 4; ++rep) {
        const int qi = wv * 4 + rep;
        const float v0 = S[qi][lane], v1 = S[qi][lane + 64];
        const float v2 = S[qi][lane + 128], v3 = S[qi][lane + 192];
        float mx = fmaxf(fmaxf(v0, v1), fmaxf(v2, v3));
#pragma unroll
        for (int m = 32; m; m >>= 1) mx = fmaxf(mx, __shfl_xor(mx, m));
        float sm = __expf(v0 - mx) + __expf(v1 - mx) + __expf(v2 - mx) + __expf(v3 - mx);
#pragma unroll
        for (int m = 32; m; m >>= 1) sm += __shfl_xor(sm, m);
        if (lane == 0) {
          const float mo = m_sh[qi], lo = l_sh[qi];
          const float mn = fmaxf(mo, mx);
          l_sh[qi] = lo * __expf(mo - mn) + sm * __expf(mx - mn);
          m_sh[qi] = mn;
        }
      }
    }
    __syncthreads();
  }
  if (t < 16) linv_sh[t] = 1.0f / l_sh[t];
  __syncthreads();

  // ---- pass 2: probabilities + V accumulation ----
  float acc0[16], acc1[16], msum[16];
#pragma unroll
  for (int qi = 0; qi < 16; ++qi) { acc0[qi] = 0.0f; acc1[qi] = 0.0f; msum[qi] = 0.0f; }

  for (int ch = 0; ch < nchunk; ++ch) {
    const int k = ch * 256 + t;
    const bool kin = (k < Lk);
    const int kc = kin ? k : (Lk - 1);
    float s[16];
    compute_scores(pq_s, pkb, kc, Lk, s);
    float ksv = 1.0f;
    if (kscale) ksv = kscale[(size_t)kc * BATCH + b];
#pragma unroll
    for (int qi = 0; qi < 16; ++qi) {
      const float p = kin ? __expf(s[qi] - m_sh[qi]) * linv_sh[qi] * ksv : 0.0f;
      S[qi][t] = p;
      msum[qi] += p;
    }
    __syncthreads();
    const int k0 = ch * 256;
    const int klim = Lk - k0;
    const int kend = (klim < 256) ? ((klim + 3) & ~3) : 256;
    for (int kk = 0; kk < kend; kk += 4) {
      float v0[4], v1[4];
#pragma unroll
      for (int j = 0; j < 4; ++j) {
        int kidx = k0 + kk + j; if (kidx >= Lk) kidx = Lk - 1;   // p=0 kills OOB contribution
        const float* vp = V + ((size_t)kidx * BATCH + b) * DMODEL;
        v0[j] = vp[t];
        v1[j] = vp[t + 256];
      }
#pragma unroll
      for (int qi = 0; qi < 16; ++qi) {
        const float4 p4 = *(const float4*)&S[qi][kk];
        acc0[qi] += p4.x * v0[0] + p4.y * v0[1] + p4.z * v0[2] + p4.w * v0[3];
        acc1[qi] += p4.x * v1[0] + p4.y * v1[1] + p4.z * v1[2] + p4.w * v1[3];
      }
    }
    __syncthreads();
  }

#pragma unroll
  for (int qi = 0; qi < 16; ++qi) {
    const int q = q0 + qi;
    if (q < Lq) {
      float* op = O + ((size_t)q * BATCH + b) * DMODEL;
      op[t] = acc0[qi];
      op[t + 256] = acc1[qi];
    }
  }

  if (maskOut) {
    __syncthreads();
#pragma unroll
    for (int qi = 0; qi < 16; ++qi) S[qi][t] = msum[qi];
    __syncthreads();
    const int wv = t >> 6, lane = t & 63;
#pragma unroll
    for (int rep = 0; rep < 4; ++rep) {
      const int qi = wv * 4 + rep;
      float sm = S[qi][lane] + S[qi][lane + 64] + S[qi][lane + 128] + S[qi][lane + 192];
#pragma unroll
      for (int m = 32; m; m >>= 1) sm += __shfl_xor(sm, m);
      const int q = q0 + qi;
      if (lane == 0 && q < Lq) maskOut[(size_t)q * BATCH + b] = sm;
    }
  }
}

// ---------------- group (img,b) elementwise + sum-of-squares kernels ----------------
// grid: (121, ngroups); block 256. Each block: 4 p-rows of one (img,b).
__global__ __launch_bounds__(256) void resid_ss_kernel(
    float* __restrict__ x, const float* __restrict__ a, float* __restrict__ ss)
{
  const int t = threadIdx.x;
  const int g = blockIdx.y;
  const int im = g >> 4, b = g & 15;
  const int p0 = blockIdx.x * 4;
  const int pr = t >> 7;
  const int c = (t & 127) * 4;
  float lsum = 0.0f;
#pragma unroll
  for (int pp = 0; pp < 2; ++pp) {
    const int p = p0 + pp * 2 + pr;
    const size_t idx = (((size_t)im * HWSZ + p) * BATCH + b) * DMODEL + c;
    float4 xv = *(float4*)(x + idx);
    const float4 av = *(const float4*)(a + idx);
    xv.x += av.x; xv.y += av.y; xv.z += av.z; xv.w += av.w;
    *(float4*)(x + idx) = xv;
    lsum += xv.x * xv.x + xv.y * xv.y + xv.z * xv.z + xv.w * xv.w;
  }
#pragma unroll
  for (int m = 32; m; m >>= 1) lsum += __shfl_xor(lsum, m);
  __shared__ float sw[4];
  if ((t & 63) == 0) sw[t >> 6] = lsum;
  __syncthreads();
  if (t == 0) atomicAdd(ss + g, sw[0] + sw[1] + sw[2] + sw[3]);
}

__global__ __launch_bounds__(256) void scale_kernel(float* __restrict__ x, const float* __restrict__ ss)
{
  const int t = threadIdx.x;
  const int g = blockIdx.y;
  const int im = g >> 4, b = g & 15;
  const int p0 = blockIdx.x * 4;
  const int pr = t >> 7;
  const int c = (t & 127) * 4;
  const float cf = inorm_coef(ss[g]);
#pragma unroll
  for (int pp = 0; pp < 2; ++pp) {
    const int p = p0 + pp * 2 + pr;
    const size_t idx = (((size_t)im * HWSZ + p) * BATCH + b) * DMODEL + c;
    float4 xv = *(float4*)(x + idx);
    xv.x *= cf; xv.y *= cf; xv.z *= cf; xv.w *= cf;
    *(float4*)(x + idx) = xv;
  }
}

// u = x*mask (in-place into x), v = x + t3 (in-place into t3); accumulate ss of both
__global__ __launch_bounds__(256) void cross_post_kernel(
    float* __restrict__ x, float* __restrict__ t3, const float* __restrict__ maskb,
    float* __restrict__ ssU, float* __restrict__ ssV)
{
  const int t = threadIdx.x;
  const int g = blockIdx.y;
  const int im = g >> 4, b = g & 15;
  const int p0 = blockIdx.x * 4;
  const int pr = t >> 7;
  const int c = (t & 127) * 4;
  float lsU = 0.0f, lsV = 0.0f;
#pragma unroll
  for (int pp = 0; pp < 2; ++pp) {
    const int p = p0 + pp * 2 + pr;
    const float mval = maskb[((size_t)im * HWSZ + p) * BATCH + b];
    const size_t idx = (((size_t)im * HWSZ + p) * BATCH + b) * DMODEL + c;
    const float4 xv = *(const float4*)(x + idx);
    const float4 tv = *(const float4*)(t3 + idx);
    float4 u, v;
    u.x = xv.x * mval; u.y = xv.y * mval; u.z = xv.z * mval; u.w = xv.w * mval;
    v.x = xv.x + tv.x; v.y = xv.y + tv.y; v.z = xv.z + tv.z; v.w = xv.w + tv.w;
    *(float4*)(x + idx) = u;
    *(float4*)(t3 + idx) = v;
    lsU += u.x * u.x + u.y * u.y + u.z * u.z + u.w * u.w;
    lsV += v.x * v.x + v.y * v.y + v.z * v.z + v.w * v.w;
  }
#pragma unroll
  for (int m = 32; m; m >>= 1) { lsU += __shfl_xor(lsU, m); lsV += __shfl_xor(lsV, m); }
  __shared__ float sw[8];
  if ((t & 63) == 0) { sw[t >> 6] = lsU; sw[4 + (t >> 6)] = lsV; }
  __syncthreads();
  if (t == 0) {
    atomicAdd(ssU + g, sw[0] + sw[1] + sw[2] + sw[3]);
    atomicAdd(ssV + g, sw[4] + sw[5] + sw[6] + sw[7]);
  }
}

// z = u*coef(ssU) + v*coef(ssV), in-place into u; accumulate ssZ
__global__ __launch_bounds__(256) void final_mix_kernel(
    float* __restrict__ u, const float* __restrict__ v,
    const float* __restrict__ ssU, const float* __restrict__ ssV, float* __restrict__ ssZ)
{
  const int t = threadIdx.x;
  const int g = blockIdx.y;
  const int im = g >> 4, b = g & 15;
  const int p0 = blockIdx.x * 4;
  const int pr = t >> 7;
  const int c = (t & 127) * 4;
  const float cu = inorm_coef(ssU[g]);
  const float cv = inorm_coef(ssV[g]);
  float lsum = 0.0f;
#pragma unroll
  for (int pp = 0; pp < 2; ++pp) {
    const int p = p0 + pp * 2 + pr;
    const size_t idx = (((size_t)im * HWSZ + p) * BATCH + b) * DMODEL + c;
    const float4 uv = *(const float4*)(u + idx);
    const float4 vv = *(const float4*)(v + idx);
    float4 z;
    z.x = uv.x * cu + vv.x * cv; z.y = uv.y * cu + vv.y * cv;
    z.z = uv.z * cu + vv.z * cv; z.w = uv.w * cu + vv.w * cv;
    *(float4*)(u + idx) = z;
    lsum += z.x * z.x + z.y * z.y + z.z * z.z + z.w * z.w;
  }
#pragma unroll
  for (int m = 32; m; m >>= 1) lsum += __shfl_xor(lsum, m);
  __shared__ float sw[4];
  if ((t & 63) == 0) sw[t >> 6] = lsum;
  __syncthreads();
  if (t == 0) atomicAdd(ssZ + g, sw[0] + sw[1] + sw[2] + sw[3]);
}

// z[(im,p,b,c)] * coef(ssZ) -> out[(row=img*16+b), c, p] (tile transpose, final inorm fused)
__global__ __launch_bounds__(256) void write_output_kernel(
    const float* __restrict__ z, const float* __restrict__ ssZ,
    float* __restrict__ out, int i0)
{
  __shared__ float tile[32][33];
  const int tx = threadIdx.x, ty = threadIdx.y;   // 32 x 8
  const int pt = blockIdx.x * 32, ct = blockIdx.y * 32;
  const int im = blockIdx.z >> 4, b = blockIdx.z & 15;
  const float sc = inorm_coef(ssZ[im * 16 + b]);
#pragma unroll
  for (int j = 0; j < 4; ++j) {
    const int p = pt + ty + 8 * j, c = ct + tx;
    tile[ty + 8 * j][tx] = (p < HWSZ)
        ? z[(((size_t)im * HWSZ + p) * BATCH + b) * DMODEL + c] * sc : 0.0f;  // tile[p_loc][c_loc]
  }
  __syncthreads();
  const int g = i0 + im;
  const size_t base = (g < 3 ? 0ull : ENC_OUT)
                    + ((size_t)(((g < 3 ? g : g - 3) * 16 + b) * 512)) * 484ull;
#pragma unroll
  for (int j = 0; j < 4; ++j) {
    const int c = ct + ty + 8 * j, p = pt + tx;
    if (p < HWSZ) out[base + (size_t)c * 484 + p] = tile[tx][ty + 8 * j];
  }
}

// ---------------- host orchestration ----------------
extern "C" void kernel_launch(void* const* d_in, const int* in_sizes, int n_in,
                              void* d_out, int out_size, void* d_ws, size_t ws_size,
                              hipStream_t stream) {
  (void)in_sizes; (void)n_in; (void)out_size;
  const float* train_feat  = (const float*)d_in[0];
  const float* test_feat   = (const float*)d_in[1];
  const float* train_label = (const float*)d_in[2];
  const float* wk_self     = (const float*)d_in[3];
  const float* bk_self     = (const float*)d_in[4];
  const float* wk_cross    = (const float*)d_in[5];
  const float* bk_cross    = (const float*)d_in[6];
  float* out = (float*)d_out;
  float* ws  = (float*)d_ws;

  // ---- workspace layout (float offsets, 64-aligned) ----
  size_t off = 0;
  auto alloc = [&](size_t n) { size_t r = off; off += (n + 63) & ~(size_t)63; return r; };
  const size_t o_pe    = alloc((size_t)HWSZ * 512);
  const size_t o_label = alloc((size_t)LENC * BATCH);
  const size_t o_ss    = alloc(1024);                 // ssE[0..47], ssA@128, ssU@256, ssV@384, ssZ@512
  const size_t o_xenc  = alloc((size_t)LENC * BATCH * DMODEL);   // also `memory`
  const size_t o_pqe   = alloc((size_t)BATCH * EKEY * LENC);
  const size_t o_pkc   = alloc((size_t)BATCH * EKEY * LENC);
  const size_t fixed = off;
  auto need_bytes = [&](int NB) -> size_t {
    size_t dec = (size_t)NB * (2ull * IMG_ELEMS + 991232ull + 7744ull);
    size_t big = dec > (size_t)LENC * BATCH * DMODEL ? dec : (size_t)LENC * BATCH * DMODEL;
    return (fixed + big) * 4 + 4096;
  };
  int NB = 6;                                    // decoder images per batch
  if (need_bytes(NB) > ws_size) NB = 3;
  if (need_bytes(NB) > ws_size) NB = 1;
  const size_t o_big = off;

  float* pe     = ws + o_pe;
  float* labelf = ws + o_label;
  float* ss     = ws + o_ss;
  float* xenc   = ws + o_xenc;                   // encoder x, becomes `memory` in place
  float* pqe    = ws + o_pqe;
  float* pkc    = ws + o_pkc;
  float* ssE = ss, *ssA = ss + 128, *ssU = ss + 256, *ssV = ss + 384, *ssZ = ss + 512;

  const size_t Z0 = 0;

  // ---- encoder ----
  init_zero_kernel<<<dim3(1), dim3(1024), 0, stream>>>(ss);
  pe_kernel<<<dim3(HWSZ), dim3(256), 0, stream>>>(pe);
  build_input_kernel<<<dim3(16, 16, 48), dim3(32, 8), 0, stream>>>(
      train_feat, test_feat, pe, 0, xenc);
  build_label_kernel<<<dim3(48), dim3(256), 0, stream>>>(train_label, labelf);
  proj_kernel<<<dim3(363), dim3(256), 0, stream>>>(xenc, wk_self, bk_self, pqe, LENC);
  {
    float* ae = ws + o_big;
    attn_kernel<<<dim3(91, 16, 1), dim3(256), 0, stream>>>(
        pqe, pqe, xenc, (const float*)nullptr, ae, (float*)nullptr,
        LENC, LENC, Z0, Z0, Z0, Z0, Z0);
    resid_ss_kernel<<<dim3(121, 48), dim3(256), 0, stream>>>(xenc, ae, ssE);
    scale_kernel<<<dim3(121, 48), dim3(256), 0, stream>>>(xenc, ssE);   // xenc == memory now
  }
  proj_kernel<<<dim3(363), dim3(256), 0, stream>>>(xenc, wk_cross, bk_cross, pkc, LENC);

  // ---- decoders (6 independent images, batched NB at a time via gridDim.z) ----
  for (int i0 = 0; i0 < 6; i0 += NB) {
    float* xd    = ws + o_big;
    float* ad    = xd + (size_t)NB * IMG_ELEMS;
    float* pqd   = ad + (size_t)NB * IMG_ELEMS;
    float* maskb = pqd + (size_t)NB * 991232;    // NB*[16][128][484]
    const size_t PQ_IS = 991232, XD_IS = IMG_ELEMS, MO_IS = (size_t)HWSZ * BATCH;

    build_input_kernel<<<dim3(16, 16, NB * 16), dim3(32, 8), 0, stream>>>(
        train_feat, test_feat, pe, i0, xd);
    // self-attention
    proj_kernel<<<dim3(NB * 121), dim3(256), 0, stream>>>(xd, wk_self, bk_self, pqd, HWSZ);
    attn_kernel<<<dim3(31, 16, NB), dim3(256), 0, stream>>>(
        pqd, pqd, xd, (const float*)nullptr, ad, (float*)nullptr,
        HWSZ, HWSZ, PQ_IS, PQ_IS, XD_IS, XD_IS, Z0);
    resid_ss_kernel<<<dim3(121, NB * 16), dim3(256), 0, stream>>>(xd, ad, ssA + i0 * 16);
    scale_kernel<<<dim3(121, NB * 16), dim3(256), 0, stream>>>(xd, ssA + i0 * 16);    // xd = x1
    // cross-attention: one softmax feeds both t3 (=sum p*label*memory) and mask (=sum p*label)
    proj_kernel<<<dim3(NB * 121), dim3(256), 0, stream>>>(xd, wk_cross, bk_cross, pqd, HWSZ);
    attn_kernel<<<dim3(31, 16, NB), dim3(256), 0, stream>>>(
        pqd, pkc, xenc /*memory*/, labelf, ad /*t3*/, maskb,
        HWSZ, LENC, PQ_IS, Z0, Z0, XD_IS, MO_IS);
    cross_post_kernel<<<dim3(121, NB * 16), dim3(256), 0, stream>>>(
        xd, ad, maskb, ssU + i0 * 16, ssV + i0 * 16);
    final_mix_kernel<<<dim3(121, NB * 16), dim3(256), 0, stream>>>(
        xd, ad, ssU + i0 * 16, ssV + i0 * 16, ssZ + i0 * 16);
    write_output_kernel<<<dim3(16, 16, NB * 16), dim3(32, 8), 0, stream>>>(
        xd, ssZ + i0 * 16, out, i0);
  }
}

// Round 2
// 1643.881 us; speedup vs baseline: 3.6129x; 3.6129x over previous
//
#include <hip/hip_runtime.h>
#include <math.h>

// ---------------- problem constants ----------------
#define BATCH   16
#define DMODEL  512
#define EKEY    128
#define HWSZ    484
#define LENC    1452                       // 3*484
#define IMG_ELEMS (HWSZ*BATCH*DMODEL)      // 3,964,928 floats per image [484][16][512]
#define ENC_OUT   11894784ull              // 3*16*512*484 (enc_feat flat size)
#define SQRT_TEMP 5.4772255750516611f      // sqrt(30); folded into BOTH normalized projections
#define INORM_SCALE 0.011048543456039806f  // sqrt(1/(512*16))
#define NEGBIG   -3.0e38f

typedef _Float16 f16;
typedef _Float16 f16x8 __attribute__((ext_vector_type(8)));
typedef _Float16 f16x4 __attribute__((ext_vector_type(4)));
typedef float    f32x4 __attribute__((ext_vector_type(4)));

__device__ __forceinline__ f32x4 mfma16(f16x8 a, f16x8 b, f32x4 c) {
  return __builtin_amdgcn_mfma_f32_16x16x32_f16(a, b, c, 0, 0, 0);
}

__device__ __forceinline__ float inorm_coef(float ss) {
  return INORM_SCALE * sqrtf(247808.0f / (ss + 1e-5f));
}

// ---------------- tiny init ----------------
__global__ void init_zero_kernel(float* __restrict__ ss) { ss[threadIdx.x] = 0.0f; }
__global__ void zero64_kernel(f16* __restrict__ p) { p[threadIdx.x] = (f16)0.0f; }

// fp32 -> fp16 (n multiple of 1024; grid = n/1024, block 256)
__global__ void cvt16_kernel(const float* __restrict__ s, f16* __restrict__ d) {
  const int i = (blockIdx.x * 256 + threadIdx.x) * 4;
  const float4 v = *(const float4*)(s + i);
  f16x4 h; h[0] = (f16)v.x; h[1] = (f16)v.y; h[2] = (f16)v.z; h[3] = (f16)v.w;
  *(f16x4*)(d + i) = h;
}

// ---------------- sinusoidal position embedding: pe[p][c], p<484, c<512 ----------------
__global__ void pe_kernel(float* __restrict__ pe) {
  const int p = blockIdx.x;
  const int j = threadIdx.x;                 // 0..255
  const float expo = (float)(2 * j) * (1.0f / 512.0f);
  const float invf = 1.0f / powf(10000.0f, expo);
  const float ang  = (float)(p + 1) * invf;
  pe[p * 512 + j]       = sinf(ang);
  pe[p * 512 + 256 + j] = cosf(ang);
}

// label[(i,b,p)] -> labT[b][i*484+p]   (contiguous in key for the softmax phase)
__global__ void build_labelT_kernel(const float* __restrict__ lab, float* __restrict__ labT) {
  const int g = blockIdx.x;                  // img*16+b, img<3
  const int im = g >> 4, b = g & 15;
  for (int p = threadIdx.x; p < HWSZ; p += blockDim.x)
    labT[(size_t)b * LENC + im * HWSZ + p] = lab[((size_t)im * BATCH + b) * HWSZ + p];
}

// ---------------- feat[(i,b,c,p)] + 1e-3*pe[p][c] -> dst[(i*484+p)][b][c] ----------------
__global__ __launch_bounds__(256) void build_input_kernel(
    const float* __restrict__ trainf, const float* __restrict__ testf,
    const float* __restrict__ pe, int i0, float* __restrict__ dst)
{
  __shared__ float tile[32][33];
  const int tx = threadIdx.x, ty = threadIdx.y;   // 32 x 8
  const int pt = blockIdx.x * 32, ct = blockIdx.y * 32;
  const int im = blockIdx.z >> 4, b = blockIdx.z & 15;
  const int g = i0 + im;                           // global image 0..5
  const float* src = (g < 3 ? trainf + (size_t)g * IMG_ELEMS
                            : testf + (size_t)(g - 3) * IMG_ELEMS)
                     + (size_t)b * (512 * 484);
#pragma unroll
  for (int j = 0; j < 4; ++j) {
    const int c = ct + ty + 8 * j, p = pt + tx;
    tile[ty + 8 * j][tx] = (p < HWSZ) ? src[(size_t)c * 484 + p] : 0.0f;
  }
  __syncthreads();
#pragma unroll
  for (int j = 0; j < 4; ++j) {
    const int p = pt + ty + 8 * j, c = ct + tx;
    if (p < HWSZ)
      dst[(((size_t)im * HWSZ + p) * BATCH + b) * DMODEL + c] =
          tile[tx][ty + 8 * j] + 1e-3f * pe[p * 512 + c];
  }
}

// ---------------- V transpose: src [(im*L+l)][b][512] f32 -> dst [(im*16+b)][512][Lp] f16 ----
// pad columns l in [L, Lp) zeroed (poison/NaN in pads would poison MFMA even at p=0)
__global__ __launch_bounds__(256) void v16t_kernel(
    const float* __restrict__ src, f16* __restrict__ dst, int L, int Lp)
{
  __shared__ f16 tile[32][33];
  const int tx = threadIdx.x, ty = threadIdx.y;   // 32 x 8
  const int l0 = blockIdx.x * 32, d0 = blockIdx.y * 32;
  const int z = blockIdx.z;                        // im*16+b
  const int im = z >> 4, b = z & 15;
#pragma unroll
  for (int j = 0; j < 4; ++j) {
    const int l = l0 + ty + 8 * j;
    float v = 0.0f;
    if (l < L) v = src[(((size_t)im * L + l) * BATCH + b) * DMODEL + d0 + tx];
    tile[ty + 8 * j][tx] = (f16)v;
  }
  __syncthreads();
#pragma unroll
  for (int j = 0; j < 4; ++j) {
    const int d = d0 + ty + 8 * j, l = l0 + tx;
    if (l < Lp) dst[((size_t)z * DMODEL + d) * (size_t)Lp + l] = tile[tx][ty + 8 * j];
  }
}

// ---------------- projection via MFMA + L2-normalize + sqrt(30) fold ----------------
// X: [M][512] f32 rows=((im*L+l)*16+b); W16: [128][512] f16; out P16: [(im*16+b)*L + l][128] f16
__global__ __launch_bounds__(256) void proj_mfma_kernel(
    const float* __restrict__ X, const f16* __restrict__ W16,
    const float* __restrict__ bias, f16* __restrict__ P16, int L)
{
  __shared__ f16 Xs[64][72];                  // row stride 144 B (16B-aligned frags)
  const int t = threadIdx.x;
  const int wave = t >> 6, lane = t & 63, quad = lane >> 4, ln = lane & 15;
  const size_t row0 = (size_t)blockIdx.x * 64;

  f32x4 acc[8];
#pragma unroll
  for (int nt = 0; nt < 8; ++nt) acc[nt] = (f32x4){0.f, 0.f, 0.f, 0.f};

  const int sr = t & 63, sko = (t >> 6) * 16;
  const float* xp = X + (row0 + sr) * 512 + sko;

  for (int k0 = 0; k0 < 512; k0 += 64) {
    {
      const float4 a0 = *(const float4*)(xp + k0);
      const float4 a1 = *(const float4*)(xp + k0 + 4);
      const float4 a2 = *(const float4*)(xp + k0 + 8);
      const float4 a3 = *(const float4*)(xp + k0 + 12);
      f16x8 h0, h1;
      h0[0]=(f16)a0.x; h0[1]=(f16)a0.y; h0[2]=(f16)a0.z; h0[3]=(f16)a0.w;
      h0[4]=(f16)a1.x; h0[5]=(f16)a1.y; h0[6]=(f16)a1.z; h0[7]=(f16)a1.w;
      h1[0]=(f16)a2.x; h1[1]=(f16)a2.y; h1[2]=(f16)a2.z; h1[3]=(f16)a2.w;
      h1[4]=(f16)a3.x; h1[5]=(f16)a3.y; h1[6]=(f16)a3.z; h1[7]=(f16)a3.w;
      *(f16x8*)&Xs[sr][sko]     = h0;
      *(f16x8*)&Xs[sr][sko + 8] = h1;
    }
    __syncthreads();
#pragma unroll
    for (int ks = 0; ks < 2; ++ks) {
      const f16x8 a = *(const f16x8*)&Xs[wave * 16 + ln][ks * 32 + quad * 8];
      const f16* wp = W16 + (size_t)ln * 512 + k0 + ks * 32 + quad * 8;
#pragma unroll
      for (int nt = 0; nt < 8; ++nt) {
        const f16x8 bf = *(const f16x8*)(wp + (size_t)nt * 16 * 512);
        acc[nt] = mfma16(a, bf, acc[nt]);
      }
    }
    __syncthreads();
  }

  float bj[8];
#pragma unroll
  for (int nt = 0; nt < 8; ++nt) bj[nt] = bias[nt * 16 + ln];

  float y[8][4]; float ssq[4] = {0.f, 0.f, 0.f, 0.f};
#pragma unroll
  for (int nt = 0; nt < 8; ++nt)
#pragma unroll
    for (int r = 0; r < 4; ++r) {
      const float v = acc[nt][r] + bj[nt];
      y[nt][r] = v; ssq[r] = fmaf(v, v, ssq[r]);
    }
#pragma unroll
  for (int r = 0; r < 4; ++r) {
    ssq[r] += __shfl_xor(ssq[r], 1); ssq[r] += __shfl_xor(ssq[r], 2);
    ssq[r] += __shfl_xor(ssq[r], 4); ssq[r] += __shfl_xor(ssq[r], 8);
  }
#pragma unroll
  for (int r = 0; r < 4; ++r) {
    const float inv = SQRT_TEMP / fmaxf(sqrtf(ssq[r]), 1e-12f);
    const size_t rg = row0 + (size_t)wave * 16 + quad * 4 + r;
    const int b = (int)(rg & 15);
    const size_t lg = rg >> 4;
    const int im = (int)(lg / (size_t)L);
    const int l  = (int)(lg - (size_t)im * L);
    f16* dp = P16 + ((size_t)(im * 16 + b) * (size_t)L + l) * 128 + ln;
#pragma unroll
    for (int nt = 0; nt < 8; ++nt) dp[nt * 16] = (f16)(y[nt][r] * inv);
  }
}

// ---------------- fused flash attention via MFMA ----------------
// pq/pk: f16 [(im*16+b)][L][128]; Vt: f16 [(im*16+b)][512][Lkp]; O: f32 [(im*L+q)][b][512]
// kscale: f32 [b][Lk] (labels, folded into P); maskOut: sum_k p*kscale per (q,b)
__global__ __launch_bounds__(256) void attn_mfma_kernel(
    const f16* __restrict__ pq, const f16* __restrict__ pk,
    const f16* __restrict__ Vt, const float* __restrict__ kscale,
    float* __restrict__ O, float* __restrict__ maskOut,
    int Lq, int Lk, int Lkp,
    size_t pq_is, size_t pk_is, size_t v_is, size_t o_is, size_t mo_is)
{
  __shared__ float Ssm[32][68];
  __shared__ f16   Psm[32][80];               // row stride 160 B (16B-aligned frags)
  __shared__ float msh[32], lsh[32], ash[32];

  const int t = threadIdx.x;
  const int wave = t >> 6, lane = t & 63, quad = lane >> 4, ln = lane & 15;
  const int b = blockIdx.y, im = blockIdx.z;
  const int q0 = blockIdx.x * 32;

  const f16* pqb = pq + (size_t)im * pq_is + (size_t)b * (size_t)Lq * 128;
  const f16* pkb = pk + (size_t)im * pk_is + (size_t)b * (size_t)Lk * 128;
  const f16* Vtb = Vt + (size_t)im * v_is  + (size_t)b * (size_t)DMODEL * (size_t)Lkp;
  float* Ob = O + (size_t)im * o_is;

  // Q fragments (A-layout: m=lane&15, k=quad*8+j)
  f16x8 qf[2][4];
#pragma unroll
  for (int mt = 0; mt < 2; ++mt) {
    int q = q0 + mt * 16 + ln; if (q > Lq - 1) q = Lq - 1;
    const f16* qp = pqb + (size_t)q * 128 + quad * 8;
#pragma unroll
    for (int es = 0; es < 4; ++es) qf[mt][es] = *(const f16x8*)(qp + es * 32);
  }

  f32x4 oacc[2][8];
#pragma unroll
  for (int mt = 0; mt < 2; ++mt)
#pragma unroll
    for (int nt = 0; nt < 8; ++nt) oacc[mt][nt] = (f32x4){0.f, 0.f, 0.f, 0.f};

  if (t < 32) { msh[t] = NEGBIG; lsh[t] = 0.f; ash[t] = 1.f; }
  float msum = 0.f;
  const int qs = t >> 3, cs = t & 7;
  const float* ksb = kscale ? kscale + (size_t)b * (size_t)Lk : (const float*)0;

  const int nch = (Lk + 63) >> 6;
  for (int ch = 0; ch < nch; ++ch) {
    const int k0 = ch << 6;
    // ---- S = Q K^T : wave handles keys k0+wave*16+ln (B n-index) ----
    {
      int kn = k0 + wave * 16 + ln; if (kn > Lk - 1) kn = Lk - 1;
      const f16* kp = pkb + (size_t)kn * 128 + quad * 8;
      f32x4 s0 = (f32x4){0.f,0.f,0.f,0.f}, s1 = (f32x4){0.f,0.f,0.f,0.f};
#pragma unroll
      for (int es = 0; es < 4; ++es) {
        const f16x8 bf = *(const f16x8*)(kp + es * 32);
        s0 = mfma16(qf[0][es], bf, s0);
        s1 = mfma16(qf[1][es], bf, s1);
      }
#pragma unroll
      for (int r = 0; r < 4; ++r) {
        Ssm[quad * 4 + r][wave * 16 + ln]      = s0[r];
        Ssm[16 + quad * 4 + r][wave * 16 + ln] = s1[r];
      }
    }
    __syncthreads();
    // ---- online softmax: thread (qs, cs) handles 8 keys ----
    {
      const f32x4 sa = *(const f32x4*)&Ssm[qs][cs * 8];
      const f32x4 sb = *(const f32x4*)&Ssm[qs][cs * 8 + 4];
      float sv[8] = {sa[0], sa[1], sa[2], sa[3], sb[0], sb[1], sb[2], sb[3]};
      const int kb = k0 + cs * 8;
#pragma unroll
      for (int j = 0; j < 8; ++j) if (kb + j >= Lk) sv[j] = NEGBIG;
      float mx = sv[0];
#pragma unroll
      for (int j = 1; j < 8; ++j) mx = fmaxf(mx, sv[j]);
      mx = fmaxf(mx, __shfl_xor(mx, 1));
      mx = fmaxf(mx, __shfl_xor(mx, 2));
      mx = fmaxf(mx, __shfl_xor(mx, 4));
      const float mold = msh[qs];
      const float mnew = fmaxf(mold, mx);
      const float alpha = __expf(mold - mnew);
      float ps = 0.f, pm = 0.f;
      f16x8 pv;
#pragma unroll
      for (int j = 0; j < 8; ++j) {
        float p = __expf(sv[j] - mnew);
        ps += p;
        if (ksb) {
          const int kk = kb + j;
          p *= (kk < Lk) ? ksb[kk] : 0.f;
        }
        pm += p;
        pv[j] = (f16)p;
      }
      *(f16x8*)&Psm[qs][cs * 8] = pv;
      ps += __shfl_xor(ps, 1); ps += __shfl_xor(ps, 2); ps += __shfl_xor(ps, 4);
      msum = msum * alpha + pm;
      if (cs == 0) { msh[qs] = mnew; lsh[qs] = lsh[qs] * alpha + ps; ash[qs] = alpha; }
    }
    __syncthreads();
    // ---- O rescale + O += P V ----
    {
      f32x4 al0, al1; bool ns = false;
#pragma unroll
      for (int r = 0; r < 4; ++r) {
        al0[r] = ash[quad * 4 + r];
        al1[r] = ash[16 + quad * 4 + r];
        ns = ns | (al0[r] != 1.f) | (al1[r] != 1.f);
      }
      if (__any(ns)) {
#pragma unroll
        for (int nt = 0; nt < 8; ++nt) { oacc[0][nt] *= al0; oacc[1][nt] *= al1; }
      }
      f16x8 pa0[2], pa1[2];
#pragma unroll
      for (int ks = 0; ks < 2; ++ks) {
        pa0[ks] = *(const f16x8*)&Psm[ln][ks * 32 + quad * 8];
        pa1[ks] = *(const f16x8*)&Psm[16 + ln][ks * 32 + quad * 8];
      }
      const f16* vp = Vtb + (size_t)(wave * 128 + ln) * (size_t)Lkp + k0 + quad * 8;
#pragma unroll
      for (int nt = 0; nt < 8; ++nt) {
        const f16* vpn = vp + (size_t)nt * 16 * (size_t)Lkp;
        const f16x8 bv0 = *(const f16x8*)(vpn);
        const f16x8 bv1 = *(const f16x8*)(vpn + 32);
        oacc[0][nt] = mfma16(pa0[0], bv0, oacc[0][nt]);
        oacc[1][nt] = mfma16(pa1[0], bv0, oacc[1][nt]);
        oacc[0][nt] = mfma16(pa0[1], bv1, oacc[0][nt]);
        oacc[1][nt] = mfma16(pa1[1], bv1, oacc[1][nt]);
      }
    }
  }
  // ---- epilogue ----
#pragma unroll
  for (int mt = 0; mt < 2; ++mt) {
    f32x4 li;
#pragma unroll
    for (int r = 0; r < 4; ++r) li[r] = 1.0f / lsh[mt * 16 + quad * 4 + r];
#pragma unroll
    for (int r = 0; r < 4; ++r) {
      const int q = q0 + mt * 16 + quad * 4 + r;
      if (q < Lq) {
        float* op = Ob + ((size_t)q * BATCH + b) * DMODEL + wave * 128 + ln;
#pragma unroll
        for (int nt = 0; nt < 8; ++nt) op[nt * 16] = oacc[mt][nt][r] * li[r];
      }
    }
  }
  if (maskOut) {
    msum += __shfl_xor(msum, 1); msum += __shfl_xor(msum, 2); msum += __shfl_xor(msum, 4);
    const int q = q0 + qs;
    if (cs == 0 && q < Lq)
      maskOut[(size_t)im * mo_is + (size_t)q * BATCH + b] = msum / lsh[qs];
  }
}

// ---------------- group (img,b) elementwise + sum-of-squares kernels (unchanged) ----------------
__global__ __launch_bounds__(256) void resid_ss_kernel(
    float* __restrict__ x, const float* __restrict__ a, float* __restrict__ ss)
{
  const int t = threadIdx.x;
  const int g = blockIdx.y;
  const int im = g >> 4, b = g & 15;
  const int p0 = blockIdx.x * 4;
  const int pr = t >> 7;
  const int c = (t & 127) * 4;
  float lsum = 0.0f;
#pragma unroll
  for (int pp = 0; pp < 2; ++pp) {
    const int p = p0 + pp * 2 + pr;
    const size_t idx = (((size_t)im * HWSZ + p) * BATCH + b) * DMODEL + c;
    float4 xv = *(float4*)(x + idx);
    const float4 av = *(const float4*)(a + idx);
    xv.x += av.x; xv.y += av.y; xv.z += av.z; xv.w += av.w;
    *(float4*)(x + idx) = xv;
    lsum += xv.x * xv.x + xv.y * xv.y + xv.z * xv.z + xv.w * xv.w;
  }
#pragma unroll
  for (int m = 32; m; m >>= 1) lsum += __shfl_xor(lsum, m);
  __shared__ float sw[4];
  if ((t & 63) == 0) sw[t >> 6] = lsum;
  __syncthreads();
  if (t == 0) atomicAdd(ss + g, sw[0] + sw[1] + sw[2] + sw[3]);
}

__global__ __launch_bounds__(256) void scale_kernel(float* __restrict__ x, const float* __restrict__ ss)
{
  const int t = threadIdx.x;
  const int g = blockIdx.y;
  const int im = g >> 4, b = g & 15;
  const int p0 = blockIdx.x * 4;
  const int pr = t >> 7;
  const int c = (t & 127) * 4;
  const float cf = inorm_coef(ss[g]);
#pragma unroll
  for (int pp = 0; pp < 2; ++pp) {
    const int p = p0 + pp * 2 + pr;
    const size_t idx = (((size_t)im * HWSZ + p) * BATCH + b) * DMODEL + c;
    float4 xv = *(float4*)(x + idx);
    xv.x *= cf; xv.y *= cf; xv.z *= cf; xv.w *= cf;
    *(float4*)(x + idx) = xv;
  }
}

__global__ __launch_bounds__(256) void cross_post_kernel(
    float* __restrict__ x, float* __restrict__ t3, const float* __restrict__ maskb,
    float* __restrict__ ssU, float* __restrict__ ssV)
{
  const int t = threadIdx.x;
  const int g = blockIdx.y;
  const int im = g >> 4, b = g & 15;
  const int p0 = blockIdx.x * 4;
  const int pr = t >> 7;
  const int c = (t & 127) * 4;
  float lsU = 0.0f, lsV = 0.0f;
#pragma unroll
  for (int pp = 0; pp < 2; ++pp) {
    const int p = p0 + pp * 2 + pr;
    const float mval = maskb[((size_t)im * HWSZ + p) * BATCH + b];
    const size_t idx = (((size_t)im * HWSZ + p) * BATCH + b) * DMODEL + c;
    const float4 xv = *(const float4*)(x + idx);
    const float4 tv = *(const float4*)(t3 + idx);
    float4 u, v;
    u.x = xv.x * mval; u.y = xv.y * mval; u.z = xv.z * mval; u.w = xv.w * mval;
    v.x = xv.x + tv.x; v.y = xv.y + tv.y; v.z = xv.z + tv.z; v.w = xv.w + tv.w;
    *(float4*)(x + idx) = u;
    *(float4*)(t3 + idx) = v;
    lsU += u.x * u.x + u.y * u.y + u.z * u.z + u.w * u.w;
    lsV += v.x * v.x + v.y * v.y + v.z * v.z + v.w * v.w;
  }
#pragma unroll
  for (int m = 32; m; m >>= 1) { lsU += __shfl_xor(lsU, m); lsV += __shfl_xor(lsV, m); }
  __shared__ float sw[8];
  if ((t & 63) == 0) { sw[t >> 6] = lsU; sw[4 + (t >> 6)] = lsV; }
  __syncthreads();
  if (t == 0) {
    atomicAdd(ssU + g, sw[0] + sw[1] + sw[2] + sw[3]);
    atomicAdd(ssV + g, sw[4] + sw[5] + sw[6] + sw[7]);
  }
}

__global__ __launch_bounds__(256) void final_mix_kernel(
    float* __restrict__ u, const float* __restrict__ v,
    const float* __restrict__ ssU, const float* __restrict__ ssV, float* __restrict__ ssZ)
{
  const int t = threadIdx.x;
  const int g = blockIdx.y;
  const int im = g >> 4, b = g & 15;
  const int p0 = blockIdx.x * 4;
  const int pr = t >> 7;
  const int c = (t & 127) * 4;
  const float cu = inorm_coef(ssU[g]);
  const float cv = inorm_coef(ssV[g]);
  float lsum = 0.0f;
#pragma unroll
  for (int pp = 0; pp < 2; ++pp) {
    const int p = p0 + pp * 2 + pr;
    const size_t idx = (((size_t)im * HWSZ + p) * BATCH + b) * DMODEL + c;
    const float4 uv = *(const float4*)(u + idx);
    const float4 vv = *(const float4*)(v + idx);
    float4 z;
    z.x = uv.x * cu + vv.x * cv; z.y = uv.y * cu + vv.y * cv;
    z.z = uv.z * cu + vv.z * cv; z.w = uv.w * cu + vv.w * cv;
    *(float4*)(u + idx) = z;
    lsum += z.x * z.x + z.y * z.y + z.z * z.z + z.w * z.w;
  }
#pragma unroll
  for (int m = 32; m; m >>= 1) lsum += __shfl_xor(lsum, m);
  __shared__ float sw[4];
  if ((t & 63) == 0) sw[t >> 6] = lsum;
  __syncthreads();
  if (t == 0) atomicAdd(ssZ + g, sw[0] + sw[1] + sw[2] + sw[3]);
}

__global__ __launch_bounds__(256) void write_output_kernel(
    const float* __restrict__ z, const float* __restrict__ ssZ,
    float* __restrict__ out, int i0)
{
  __shared__ float tile[32][33];
  const int tx = threadIdx.x, ty = threadIdx.y;   // 32 x 8
  const int pt = blockIdx.x * 32, ct = blockIdx.y * 32;
  const int im = blockIdx.z >> 4, b = blockIdx.z & 15;
  const float sc = inorm_coef(ssZ[im * 16 + b]);
#pragma unroll
  for (int j = 0; j < 4; ++j) {
    const int p = pt + ty + 8 * j, c = ct + tx;
    tile[ty + 8 * j][tx] = (p < HWSZ)
        ? z[(((size_t)im * HWSZ + p) * BATCH + b) * DMODEL + c] * sc : 0.0f;
  }
  __syncthreads();
  const int g = i0 + im;
  const size_t base = (g < 3 ? 0ull : ENC_OUT)
                    + ((size_t)(((g < 3 ? g : g - 3) * 16 + b) * 512)) * 484ull;
#pragma unroll
  for (int j = 0; j < 4; ++j) {
    const int c = ct + ty + 8 * j, p = pt + tx;
    if (p < HWSZ) out[base + (size_t)c * 484 + p] = tile[tx][ty + 8 * j];
  }
}

// ---------------- host orchestration ----------------
extern "C" void kernel_launch(void* const* d_in, const int* in_sizes, int n_in,
                              void* d_out, int out_size, void* d_ws, size_t ws_size,
                              hipStream_t stream) {
  (void)in_sizes; (void)n_in; (void)out_size;
  const float* train_feat  = (const float*)d_in[0];
  const float* test_feat   = (const float*)d_in[1];
  const float* train_label = (const float*)d_in[2];
  const float* wk_self     = (const float*)d_in[3];
  const float* bk_self     = (const float*)d_in[4];
  const float* wk_cross    = (const float*)d_in[5];
  const float* bk_cross    = (const float*)d_in[6];
  float* out = (float*)d_out;
  char* wsb  = (char*)d_ws;

  // ---- workspace layout (byte offsets, 256-aligned) ----
  size_t off = 0;
  auto alloc = [&](size_t bytes) { size_t r = off; off = (r + bytes + 255) & ~(size_t)255; return r; };
  const size_t o_pe   = alloc(991232ull);                 // pe [484][512] f32
  const size_t o_labT = alloc(16ull * LENC * 4);          // labT [16][1452] f32
  const size_t o_ss   = alloc(4096);
  const size_t o_w16s = alloc(131072);                    // wk_self f16
  const size_t o_w16c = alloc(131072);                    // wk_cross f16
  const size_t o_xenc = alloc(47579136ull);               // [1452][16][512] f32
  const size_t o_p16  = alloc(5947392ull);                // pq16_enc, later pkc16 (f16)
  const size_t o_vt   = alloc((11927552ull + 64) * 2);    // Vt_enc, later Vt_mem (f16, Lkp=1456)
  const size_t o_big  = off;

  float* pe   = (float*)(wsb + o_pe);
  float* labT = (float*)(wsb + o_labT);
  float* ss   = (float*)(wsb + o_ss);
  f16*   w16s = (f16*)(wsb + o_w16s);
  f16*   w16c = (f16*)(wsb + o_w16c);
  float* xenc = (float*)(wsb + o_xenc);
  f16*   p16  = (f16*)(wsb + o_p16);
  f16*   vt   = (f16*)(wsb + o_vt);
  char*  bigb = wsb + o_big;
  float* ssE = ss, *ssA = ss + 128, *ssU = ss + 256, *ssV = ss + 384, *ssZ = ss + 512;

  auto dec_bytes = [&](int NB) -> size_t {
    size_t per = 0;
    per += (size_t)NB * IMG_ELEMS * 4;            // xd
    per += (size_t)NB * IMG_ELEMS * 4;            // ad
    per += (size_t)NB * 991232ull * 2;            // pq16_d [16][484][128] f16
    per += ((size_t)NB * 3997696ull + 64) * 2;    // Vt_d [16][512][488] f16 + slack
    per += (size_t)NB * 7744 * 4;                 // maskb
    per += 2048;
    return per;
  };
  const size_t encb = 47579136ull;                // ae
  int NB = 6;
  if (o_big + (dec_bytes(NB) > encb ? dec_bytes(NB) : encb) > ws_size) NB = 3;
  if (o_big + (dec_bytes(NB) > encb ? dec_bytes(NB) : encb) > ws_size) NB = 1;

  // ---- encoder ----
  init_zero_kernel<<<dim3(1), dim3(1024), 0, stream>>>(ss);
  pe_kernel<<<dim3(HWSZ), dim3(256), 0, stream>>>(pe);
  build_input_kernel<<<dim3(16, 16, 48), dim3(32, 8), 0, stream>>>(
      train_feat, test_feat, pe, 0, xenc);
  build_labelT_kernel<<<dim3(48), dim3(256), 0, stream>>>(train_label, labT);
  cvt16_kernel<<<dim3(64), dim3(256), 0, stream>>>(wk_self, w16s);
  cvt16_kernel<<<dim3(64), dim3(256), 0, stream>>>(wk_cross, w16c);
  v16t_kernel<<<dim3(46, 16, 16), dim3(32, 8), 0, stream>>>(xenc, vt, LENC, 1456);
  zero64_kernel<<<dim3(1), dim3(64), 0, stream>>>(vt + 11927552ull);
  proj_mfma_kernel<<<dim3(363), dim3(256), 0, stream>>>(xenc, w16s, bk_self, p16, LENC);
  {
    float* ae = (float*)bigb;
    attn_mfma_kernel<<<dim3(46, 16, 1), dim3(256), 0, stream>>>(
        p16, p16, vt, (const float*)0, ae, (float*)0,
        LENC, LENC, 1456, 0, 0, 0, 0, 0);
    resid_ss_kernel<<<dim3(121, 48), dim3(256), 0, stream>>>(xenc, ae, ssE);
    scale_kernel<<<dim3(121, 48), dim3(256), 0, stream>>>(xenc, ssE);   // xenc == memory
  }
  proj_mfma_kernel<<<dim3(363), dim3(256), 0, stream>>>(xenc, w16c, bk_cross, p16, LENC); // pkc16
  v16t_kernel<<<dim3(46, 16, 16), dim3(32, 8), 0, stream>>>(xenc, vt, LENC, 1456);        // Vt_mem
  zero64_kernel<<<dim3(1), dim3(64), 0, stream>>>(vt + 11927552ull);

  // ---- decoders (6 independent images, NB at a time) ----
  for (int i0 = 0; i0 < 6; i0 += NB) {
    float* xd    = (float*)bigb;
    float* ad    = xd + (size_t)NB * IMG_ELEMS;
    f16*   pq16d = (f16*)(ad + (size_t)NB * IMG_ELEMS);
    f16*   vtd   = pq16d + (size_t)NB * 991232ull;
    float* maskb = (float*)(vtd + (size_t)NB * 3997696ull + 64);

    build_input_kernel<<<dim3(16, 16, NB * 16), dim3(32, 8), 0, stream>>>(
        train_feat, test_feat, pe, i0, xd);
    v16t_kernel<<<dim3(16, 16, NB * 16), dim3(32, 8), 0, stream>>>(xd, vtd, HWSZ, 488);
    zero64_kernel<<<dim3(1), dim3(64), 0, stream>>>(vtd + (size_t)NB * 3997696ull);
    // self-attention
    proj_mfma_kernel<<<dim3(NB * 121), dim3(256), 0, stream>>>(xd, w16s, bk_self, pq16d, HWSZ);
    attn_mfma_kernel<<<dim3(16, 16, NB), dim3(256), 0, stream>>>(
        pq16d, pq16d, vtd, (const float*)0, ad, (float*)0,
        HWSZ, HWSZ, 488, 991232ull, 991232ull, 3997696ull, (size_t)IMG_ELEMS, 0);
    resid_ss_kernel<<<dim3(121, NB * 16), dim3(256), 0, stream>>>(xd, ad, ssA + i0 * 16);
    scale_kernel<<<dim3(121, NB * 16), dim3(256), 0, stream>>>(xd, ssA + i0 * 16);
    // cross-attention: one softmax feeds both t3 (sum p*label*memory) and mask (sum p*label)
    proj_mfma_kernel<<<dim3(NB * 121), dim3(256), 0, stream>>>(xd, w16c, bk_cross, pq16d, HWSZ);
    attn_mfma_kernel<<<dim3(16, 16, NB), dim3(256), 0, stream>>>(
        pq16d, p16 /*pkc16*/, vt /*Vt_mem*/, labT, ad /*t3*/, maskb,
        HWSZ, LENC, 1456, 991232ull, 0, 0, (size_t)IMG_ELEMS, 7744);
    cross_post_kernel<<<dim3(121, NB * 16), dim3(256), 0, stream>>>(
        xd, ad, maskb, ssU + i0 * 16, ssV + i0 * 16);
    final_mix_kernel<<<dim3(121, NB * 16), dim3(256), 0, stream>>>(
        xd, ad, ssU + i0 * 16, ssV + i0 * 16, ssZ + i0 * 16);
    write_output_kernel<<<dim3(16, 16, NB * 16), dim3(32, 8), 0, stream>>>(
        xd, ssZ + i0 * 16, out, i0);
  }
}

// Round 3
// 1250.159 us; speedup vs baseline: 4.7508x; 1.3149x over previous
//
#include <hip/hip_runtime.h>
#include <math.h>

// ---------------- problem constants ----------------
#define BATCH   16
#define DMODEL  512
#define EKEY    128
#define HWSZ    484
#define LENC    1452
#define IMG_ELEMS (HWSZ*BATCH*DMODEL)      // 3,964,928 floats per image [484][16][512]
#define ENC_OUT   11894784ull
#define SQRT_TEMP 5.4772255750516611f      // sqrt(30) folded into both projections
#define INORM_SCALE 0.011048543456039806f  // sqrt(1/(512*16))
#define NEGBIG   -3.0e38f

typedef _Float16 f16;
typedef _Float16 f16x8 __attribute__((ext_vector_type(8)));
typedef _Float16 f16x4 __attribute__((ext_vector_type(4)));
typedef float    f32x4 __attribute__((ext_vector_type(4)));

__device__ __forceinline__ f32x4 mfma16(f16x8 a, f16x8 b, f32x4 c) {
  return __builtin_amdgcn_mfma_f32_16x16x32_f16(a, b, c, 0, 0, 0);
}
__device__ __forceinline__ float inorm_coef(float ss) {
  return INORM_SCALE * sqrtf(247808.0f / (ss + 1e-5f));
}

// ---------------- tiny kernels ----------------
__global__ void init_zero_kernel(float* __restrict__ ss) { ss[threadIdx.x] = 0.0f; }

// peT[c][p]: transposed sinusoidal embedding (coalesced consumption in build_input)
__global__ void peT_kernel(float* __restrict__ peT) {
  const int c = blockIdx.x;                  // 0..511
  const int cc = (c < 256) ? c : c - 256;
  const float invf = 1.0f / powf(10000.0f, (float)(2 * cc) * (1.0f / 512.0f));
  for (int p = threadIdx.x; p < HWSZ; p += blockDim.x) {
    const float ang = (float)(p + 1) * invf;
    peT[c * HWSZ + p] = (c < 256) ? sinf(ang) : cosf(ang);
  }
}

// label[(i,b,p)] -> labT[b][i*484+p]
__global__ void build_labelT_kernel(const float* __restrict__ lab, float* __restrict__ labT) {
  const int g = blockIdx.x;
  const int im = g >> 4, b = g & 15;
  for (int p = threadIdx.x; p < HWSZ; p += blockDim.x)
    labT[(size_t)b * LENC + im * HWSZ + p] = lab[((size_t)im * BATCH + b) * HWSZ + p];
}

__global__ void cvt16_kernel(const float* __restrict__ s, f16* __restrict__ d) {
  const int i = (blockIdx.x * 256 + threadIdx.x) * 4;
  const float4 v = *(const float4*)(s + i);
  f16x4 h; h[0] = (f16)v.x; h[1] = (f16)v.y; h[2] = (f16)v.z; h[3] = (f16)v.w;
  *(f16x4*)(d + i) = h;
}

// feat + 1e-3*pe -> xout f32 [(im*484+p)][b][512]  AND  vt f16 [z][512][Lkp] (V in source layout)
__global__ __launch_bounds__(256) void build_input_kernel(
    const float* __restrict__ trainf, const float* __restrict__ testf,
    const float* __restrict__ peT, int i0, float* __restrict__ xout,
    f16* __restrict__ vt, int zmul, int col_im_step, int Lkp)
{
  __shared__ float tile[32][33];
  const int tx = threadIdx.x, ty = threadIdx.y;   // 32 x 8
  const int pt = blockIdx.x * 32, ct = blockIdx.y * 32;
  const int im = blockIdx.z >> 4, b = blockIdx.z & 15;
  const int g = i0 + im;
  const float* src = (g < 3 ? trainf + (size_t)g * IMG_ELEMS
                            : testf + (size_t)(g - 3) * IMG_ELEMS)
                     + (size_t)b * (512 * 484);
  const int zv = zmul ? (im * 16 + b) : b;
  const int col0 = im * col_im_step;
#pragma unroll
  for (int j = 0; j < 4; ++j) {
    const int c = ct + ty + 8 * j, p = pt + tx;
    float val = 0.0f;
    if (p < HWSZ) {
      val = src[(size_t)c * 484 + p] + 1e-3f * peT[(size_t)c * 484 + p];
      vt[((size_t)zv * 512 + c) * (size_t)Lkp + col0 + p] = (f16)val;
    }
    tile[ty + 8 * j][tx] = val;               // tile[c_loc][p_loc]
  }
  __syncthreads();
#pragma unroll
  for (int j = 0; j < 4; ++j) {
    const int p = pt + ty + 8 * j, c = ct + tx;
    if (p < HWSZ)
      xout[(((size_t)im * HWSZ + p) * BATCH + b) * DMODEL + c] = tile[tx][ty + 8 * j];
  }
}

// memory (xenc, unnormalized) * cf -> Vt_mem f16 [b][512][1472] (tile transpose)
__global__ __launch_bounds__(256) void v16t_mem_kernel(
    const float* __restrict__ src, const float* __restrict__ ssE, f16* __restrict__ dst)
{
  __shared__ f16 tile[32][33];
  const int tx = threadIdx.x, ty = threadIdx.y;
  const int l0 = blockIdx.x * 32, d0 = blockIdx.y * 32;
  const int b = blockIdx.z;
#pragma unroll
  for (int j = 0; j < 4; ++j) {
    const int l = l0 + ty + 8 * j;
    float v = 0.0f;
    if (l < LENC) {
      const float cf = inorm_coef(ssE[(l / 484) * 16 + b]);
      v = cf * src[((size_t)l * BATCH + b) * DMODEL + d0 + tx];
    }
    tile[ty + 8 * j][tx] = (f16)v;            // tile[l_loc][d_loc]
  }
  __syncthreads();
#pragma unroll
  for (int j = 0; j < 4; ++j) {
    const int d = d0 + ty + 8 * j, l = l0 + tx;
    if (l < 1472) dst[((size_t)b * 512 + d) * 1472 + l] = tile[tx][ty + 8 * j];
  }
}

// ---------------- projection via MFMA + optional group scale + L2-normalize + sqrt(30) ----
// X: [M][512] f32 rows=((im*L+l)*16+b); ssg: group ss (cf per (l/484,b)) or null
__global__ __launch_bounds__(256) void proj_mfma_kernel(
    const float* __restrict__ X, const f16* __restrict__ W16,
    const float* __restrict__ bias, const float* __restrict__ ssg,
    f16* __restrict__ P16, int L)
{
  __shared__ f16 Xs[64][72];
  const int t = threadIdx.x;
  const int wave = t >> 6, lane = t & 63, quad = lane >> 4, ln = lane & 15;
  const size_t row0 = (size_t)blockIdx.x * 64;

  f32x4 acc[8];
#pragma unroll
  for (int nt = 0; nt < 8; ++nt) acc[nt] = (f32x4){0.f, 0.f, 0.f, 0.f};

  const int sr = t & 63, sko = (t >> 6) * 16;
  const size_t rowg = row0 + sr;
  float cf = 1.0f;
  if (ssg) {
    const int bb = (int)(rowg & 15);
    const int gg = (int)((rowg >> 4) / 484);
    cf = inorm_coef(ssg[gg * 16 + bb]);
  }
  const float* xp = X + rowg * 512 + sko;

  for (int k0 = 0; k0 < 512; k0 += 64) {
    {
      const float4 a0 = *(const float4*)(xp + k0);
      const float4 a1 = *(const float4*)(xp + k0 + 4);
      const float4 a2 = *(const float4*)(xp + k0 + 8);
      const float4 a3 = *(const float4*)(xp + k0 + 12);
      f16x8 h0, h1;
      h0[0]=(f16)(cf*a0.x); h0[1]=(f16)(cf*a0.y); h0[2]=(f16)(cf*a0.z); h0[3]=(f16)(cf*a0.w);
      h0[4]=(f16)(cf*a1.x); h0[5]=(f16)(cf*a1.y); h0[6]=(f16)(cf*a1.z); h0[7]=(f16)(cf*a1.w);
      h1[0]=(f16)(cf*a2.x); h1[1]=(f16)(cf*a2.y); h1[2]=(f16)(cf*a2.z); h1[3]=(f16)(cf*a2.w);
      h1[4]=(f16)(cf*a3.x); h1[5]=(f16)(cf*a3.y); h1[6]=(f16)(cf*a3.z); h1[7]=(f16)(cf*a3.w);
      *(f16x8*)&Xs[sr][sko]     = h0;
      *(f16x8*)&Xs[sr][sko + 8] = h1;
    }
    __syncthreads();
#pragma unroll
    for (int ks = 0; ks < 2; ++ks) {
      const f16x8 a = *(const f16x8*)&Xs[wave * 16 + ln][ks * 32 + quad * 8];
      const f16* wp = W16 + (size_t)ln * 512 + k0 + ks * 32 + quad * 8;
#pragma unroll
      for (int nt = 0; nt < 8; ++nt) {
        const f16x8 bf = *(const f16x8*)(wp + (size_t)nt * 16 * 512);
        acc[nt] = mfma16(a, bf, acc[nt]);
      }
    }
    __syncthreads();
  }

  float bj[8];
#pragma unroll
  for (int nt = 0; nt < 8; ++nt) bj[nt] = bias[nt * 16 + ln];

  float y[8][4]; float ssq[4] = {0.f, 0.f, 0.f, 0.f};
#pragma unroll
  for (int nt = 0; nt < 8; ++nt)
#pragma unroll
    for (int r = 0; r < 4; ++r) {
      const float v = acc[nt][r] + bj[nt];
      y[nt][r] = v; ssq[r] = fmaf(v, v, ssq[r]);
    }
#pragma unroll
  for (int r = 0; r < 4; ++r) {
    ssq[r] += __shfl_xor(ssq[r], 1); ssq[r] += __shfl_xor(ssq[r], 2);
    ssq[r] += __shfl_xor(ssq[r], 4); ssq[r] += __shfl_xor(ssq[r], 8);
  }
#pragma unroll
  for (int r = 0; r < 4; ++r) {
    const float inv = SQRT_TEMP / fmaxf(sqrtf(ssq[r]), 1e-12f);
    const size_t rg = row0 + (size_t)wave * 16 + quad * 4 + r;
    const int b = (int)(rg & 15);
    const size_t lg = rg >> 4;
    const int im = (int)(lg / (size_t)L);
    const int l  = (int)(lg - (size_t)im * L);
    f16* dp = P16 + ((size_t)(im * 16 + b) * (size_t)L + l) * 128 + ln;
#pragma unroll
    for (int nt = 0; nt < 8; ++nt) dp[nt * 16] = (f16)(y[nt][r] * inv);
  }
}

// ---------------- fused flash attention v3 ----------------
// 64q x 512d per block (8 waves). wave: QK n-tile = (wave&3), m-pair = (wave>>2);
// PV d-slice = wave*64. b-affinity: blockIdx%8 selects b%8 (XCD L2 locality).
// !CROSS: X += O, atomic ssO per inorm group (handles 484-boundary straddle).
// CROSS : u=x1*mask in-place into X, v=x1+t3 into Vout, atomics ssU/ssV/ssUV.
template<int CROSS>
__global__ __launch_bounds__(512, 2) void attn3_kernel(
    const f16* __restrict__ pq, const f16* __restrict__ pk, const f16* __restrict__ Vt,
    const float* __restrict__ labT, float* __restrict__ X, float* __restrict__ Vout,
    const float* __restrict__ ssIn, float* __restrict__ ssO,
    float* __restrict__ ssV_, float* __restrict__ ssUV_,
    int Lq, int Lk, int Lkp, int nqb, int pk_shared, int vt_shared)
{
  __shared__ float Ssm[64][68];
  __shared__ f16   Psm[64][80];
  __shared__ float msh[64], lsh[64], ash[64], mask_sh[64];

  const int t = threadIdx.x;
  const int wave = t >> 6, lane = t & 63, quad = lane >> 4, ln = lane & 15;
  const int mtp = wave >> 2, kt = wave & 3;

  const int id = blockIdx.x;
  const int b  = (id & 7) + 8 * ((id >> 3) & 1);
  const int jj = id >> 4;
  const int qb = jj % nqb, im = jj / nqb;
  const int q0 = qb * 64;
  const int zq = im * 16 + b;
  const int zk = pk_shared ? b : zq;
  const int zv = vt_shared ? b : zq;

  const f16* pqb = pq + (size_t)zq * Lq * 128;
  const f16* pkb = pk + (size_t)zk * Lk * 128;
  const f16* Vtb = Vt + (size_t)zv * 512 * (size_t)Lkp;
  const float* ksb = CROSS ? labT + (size_t)b * Lk : (const float*)0;

  // Q fragments for this wave's two m-tiles
  f16x8 qf[2][4];
#pragma unroll
  for (int i = 0; i < 2; ++i) {
    int q = q0 + (2 * mtp + i) * 16 + ln; if (q > Lq - 1) q = Lq - 1;
    const f16* qp = pqb + (size_t)q * 128 + quad * 8;
#pragma unroll
    for (int es = 0; es < 4; ++es) qf[i][es] = *(const f16x8*)(qp + es * 32);
  }

  f32x4 oacc[4][4];
#pragma unroll
  for (int mt = 0; mt < 4; ++mt)
#pragma unroll
    for (int nt = 0; nt < 4; ++nt) oacc[mt][nt] = (f32x4){0.f, 0.f, 0.f, 0.f};

  if (t < 64) { msh[t] = NEGBIG; lsh[t] = 0.f; ash[t] = 0.f; }
  float msum = 0.f;
  const int qs = t >> 3, cs = t & 7;
  __syncthreads();

  const int nch = (Lk + 63) >> 6;
  for (int ch = 0; ch < nch; ++ch) {
    const int k0 = ch << 6;
    // ---- S = Q K^T ----
    {
      int kn = k0 + kt * 16 + ln; if (kn > Lk - 1) kn = Lk - 1;
      const f16* kp = pkb + (size_t)kn * 128 + quad * 8;
      f32x4 s0 = (f32x4){0.f,0.f,0.f,0.f}, s1 = (f32x4){0.f,0.f,0.f,0.f};
#pragma unroll
      for (int es = 0; es < 4; ++es) {
        const f16x8 kf = *(const f16x8*)(kp + es * 32);
        s0 = mfma16(qf[0][es], kf, s0);
        s1 = mfma16(qf[1][es], kf, s1);
      }
#pragma unroll
      for (int r = 0; r < 4; ++r) {
        Ssm[(2 * mtp) * 16 + quad * 4 + r][kt * 16 + ln]     = s0[r];
        Ssm[(2 * mtp + 1) * 16 + quad * 4 + r][kt * 16 + ln] = s1[r];
      }
    }
    __syncthreads();
    // ---- online softmax: thread (qs, cs) owns 8 keys of q-row qs ----
    {
      const f32x4 sa = *(const f32x4*)&Ssm[qs][cs * 8];
      const f32x4 sb = *(const f32x4*)&Ssm[qs][cs * 8 + 4];
      float sv[8] = {sa[0], sa[1], sa[2], sa[3], sb[0], sb[1], sb[2], sb[3]};
      const int kb = k0 + cs * 8;
#pragma unroll
      for (int j = 0; j < 8; ++j) if (kb + j >= Lk) sv[j] = NEGBIG;
      float mx = sv[0];
#pragma unroll
      for (int j = 1; j < 8; ++j) mx = fmaxf(mx, sv[j]);
      mx = fmaxf(mx, __shfl_xor(mx, 1));
      mx = fmaxf(mx, __shfl_xor(mx, 2));
      mx = fmaxf(mx, __shfl_xor(mx, 4));
      const float mold = msh[qs];
      const float mnew = fmaxf(mold, mx);
      const float alpha = __expf(mold - mnew);
      float ps = 0.f, pm = 0.f;
      f16x8 pv;
#pragma unroll
      for (int j = 0; j < 8; ++j) {
        float p = __expf(sv[j] - mnew);
        ps += p;
        if (CROSS) {
          const int kk = kb + j;
          p *= (kk < Lk) ? ksb[kk] : 0.f;
        }
        pm += p;
        pv[j] = (f16)p;
      }
      *(f16x8*)&Psm[qs][cs * 8] = pv;
      ps += __shfl_xor(ps, 1); ps += __shfl_xor(ps, 2); ps += __shfl_xor(ps, 4);
      msum = msum * alpha + pm;
      if (cs == 0) { msh[qs] = mnew; lsh[qs] = lsh[qs] * alpha + ps; ash[qs] = alpha; }
    }
    __syncthreads();
    // ---- O rescale + O += P V  (wave's 64-d slice, all 64 q) ----
    {
      f16x8 pa[4][2];
#pragma unroll
      for (int mt = 0; mt < 4; ++mt)
#pragma unroll
        for (int ks = 0; ks < 2; ++ks)
          pa[mt][ks] = *(const f16x8*)&Psm[mt * 16 + ln][ks * 32 + quad * 8];
#pragma unroll
      for (int mt = 0; mt < 4; ++mt) {
        f32x4 al;
#pragma unroll
        for (int r = 0; r < 4; ++r) al[r] = ash[mt * 16 + quad * 4 + r];
#pragma unroll
        for (int nt = 0; nt < 4; ++nt) oacc[mt][nt] *= al;
      }
      const f16* vp = Vtb + (size_t)(wave * 64 + ln) * (size_t)Lkp + k0 + quad * 8;
      f16x8 bv[4][2];
#pragma unroll
      for (int nt = 0; nt < 4; ++nt) {
        const f16* vpn = vp + (size_t)nt * 16 * (size_t)Lkp;
        bv[nt][0] = *(const f16x8*)(vpn);
        bv[nt][1] = *(const f16x8*)(vpn + 32);
      }
#pragma unroll
      for (int nt = 0; nt < 4; ++nt)
#pragma unroll
        for (int ks = 0; ks < 2; ++ks)
#pragma unroll
          for (int mt = 0; mt < 4; ++mt)
            oacc[mt][nt] = mfma16(pa[mt][ks], bv[nt][ks], oacc[mt][nt]);
    }
  }

  // ---- epilogue ----
  if (CROSS) {
    float ms = msum;
    ms += __shfl_xor(ms, 1); ms += __shfl_xor(ms, 2); ms += __shfl_xor(ms, 4);
    if (cs == 0) mask_sh[qs] = ms / lsh[qs];
    __syncthreads();
  }

  const int g0  = (im * Lq + q0) / 484;
  const int bhi = (g0 + 1) * 484 - im * Lq;             // local-q group boundary
  const bool strad = (!CROSS) && (bhi < Lq) && (bhi < q0 + 64);

  float a0 = 0.f, a1 = 0.f, a2 = 0.f;
  const float cfA = CROSS ? inorm_coef(ssIn[im * 16 + b]) : 0.f;

#pragma unroll
  for (int mt = 0; mt < 4; ++mt) {
    f32x4 li;
#pragma unroll
    for (int r = 0; r < 4; ++r) li[r] = 1.0f / lsh[mt * 16 + quad * 4 + r];
#pragma unroll
    for (int r = 0; r < 4; ++r) {
      const int q = q0 + mt * 16 + quad * 4 + r;
      if (q < Lq) {
        const size_t base = (((size_t)(im * Lq + q)) * BATCH + b) * DMODEL + wave * 64 + ln;
        if (!CROSS) {
          const bool hi = (q >= bhi);
#pragma unroll
          for (int nt = 0; nt < 4; ++nt) {
            const float y = X[base + nt * 16] + oacc[mt][nt][r] * li[r];
            X[base + nt * 16] = y;
            if (hi) a1 += y * y; else a0 += y * y;
          }
        } else {
          const float mval = mask_sh[mt * 16 + quad * 4 + r];
#pragma unroll
          for (int nt = 0; nt < 4; ++nt) {
            const float x1 = cfA * X[base + nt * 16];
            const float u = x1 * mval;
            const float v = x1 + oacc[mt][nt][r] * li[r];
            X[base + nt * 16] = u;
            Vout[base + nt * 16] = v;
            a0 += u * u; a1 += v * v; a2 += u * v;
          }
        }
      }
    }
  }
#pragma unroll
  for (int m = 32; m; m >>= 1) {
    a0 += __shfl_xor(a0, m); a1 += __shfl_xor(a1, m);
    if (CROSS) a2 += __shfl_xor(a2, m);
  }
  if (lane == 0) {
    if (!CROSS) {
      atomicAdd(ssO + g0 * 16 + b, a0);
      if (strad) atomicAdd(ssO + (g0 + 1) * 16 + b, a1);
    } else {
      const int g = im * 16 + b;
      atomicAdd(ssO + g, a0);
      atomicAdd(ssV_ + g, a1);
      atomicAdd(ssUV_ + g, a2);
    }
  }
}

// cu*cz, cv*cz per group (exact ssZ expansion)
__global__ void coef_final_kernel(const float* __restrict__ ssU, const float* __restrict__ ssV,
                                  const float* __restrict__ ssUV, float* __restrict__ AB, int n)
{
  const int t = threadIdx.x;
  if (t < n) {
    const float su = ssU[t], sv = ssV[t], suv = ssUV[t];
    const float cu = inorm_coef(su), cv = inorm_coef(sv);
    const float ssz = cu * cu * su + cv * cv * sv + 2.f * cu * cv * suv;
    const float cz = inorm_coef(ssz);
    AB[2 * t] = cu * cz; AB[2 * t + 1] = cv * cz;
  }
}

// out[b][c][p] = A*u[(im,p,b,c)] + B*v[...]  (fused final mix + inorm + transpose)
__global__ __launch_bounds__(256) void final_out_kernel(
    const float* __restrict__ u, const float* __restrict__ v,
    const float* __restrict__ AB, float* __restrict__ out, int i0)
{
  __shared__ float tile[32][33];
  const int tx = threadIdx.x, ty = threadIdx.y;
  const int pt = blockIdx.x * 32, ct = blockIdx.y * 32;
  const int z = blockIdx.z;
  const int im = z >> 4, b = z & 15;
  const float A = AB[2 * z], B = AB[2 * z + 1];
#pragma unroll
  for (int j = 0; j < 4; ++j) {
    const int p = pt + ty + 8 * j, c = ct + tx;
    float val = 0.0f;
    if (p < HWSZ) {
      const size_t idx = (((size_t)im * HWSZ + p) * BATCH + b) * DMODEL + c;
      val = A * u[idx] + B * v[idx];
    }
    tile[ty + 8 * j][tx] = val;               // tile[p_loc][c_loc]
  }
  __syncthreads();
  const int g = i0 + im;
  const size_t base = (g < 3 ? 0ull : ENC_OUT)
                    + ((size_t)(((g < 3 ? g : g - 3) * 16 + b) * 512)) * 484ull;
#pragma unroll
  for (int j = 0; j < 4; ++j) {
    const int c = ct + ty + 8 * j, p = pt + tx;
    if (p < HWSZ) out[base + (size_t)c * 484 + p] = tile[tx][ty + 8 * j];
  }
}

// ---------------- host orchestration ----------------
extern "C" void kernel_launch(void* const* d_in, const int* in_sizes, int n_in,
                              void* d_out, int out_size, void* d_ws, size_t ws_size,
                              hipStream_t stream) {
  (void)in_sizes; (void)n_in; (void)out_size;
  const float* train_feat  = (const float*)d_in[0];
  const float* test_feat   = (const float*)d_in[1];
  const float* train_label = (const float*)d_in[2];
  const float* wk_self     = (const float*)d_in[3];
  const float* bk_self     = (const float*)d_in[4];
  const float* wk_cross    = (const float*)d_in[5];
  const float* bk_cross    = (const float*)d_in[6];
  float* out = (float*)d_out;
  char* wsb  = (char*)d_ws;

  size_t off = 0;
  auto alloc = [&](size_t bytes) { size_t r = off; off = (r + bytes + 255) & ~(size_t)255; return r; };
  const size_t o_peT   = alloc(991232ull);             // [512][484] f32
  const size_t o_labT  = alloc(16ull * LENC * 4);
  const size_t o_ss    = alloc(4096);                  // ssE@0 ssA@128 ssU@256 ssV@384 ssUV@512 AB@640
  const size_t o_w16s  = alloc(131072);
  const size_t o_w16c  = alloc(131072);
  const size_t o_xenc  = alloc(47579136ull);           // [1452][16][512] f32
  const size_t o_p16   = alloc(5947392ull);            // enc pq, later pkc
  const size_t o_vte   = alloc(16ull*512*1472*2);      // Vt_enc (input x as V)
  const size_t o_vtm   = alloc(16ull*512*1472*2);      // Vt_mem
  const size_t fixed = off;

  float* peT  = (float*)(wsb + o_peT);
  float* labT = (float*)(wsb + o_labT);
  float* ss   = (float*)(wsb + o_ss);
  f16*   w16s = (f16*)(wsb + o_w16s);
  f16*   w16c = (f16*)(wsb + o_w16c);
  float* xenc = (float*)(wsb + o_xenc);
  f16*   p16  = (f16*)(wsb + o_p16);
  f16*   vte  = (f16*)(wsb + o_vte);
  f16*   vtm  = (f16*)(wsb + o_vtm);
  float* ssE = ss, *ssA = ss + 128, *ssU = ss + 256, *ssV = ss + 384, *ssUV = ss + 512;
  float* AB  = ss + 640;

  const size_t decPer = 15859712ull * 2 + 1982464ull + 8388608ull;  // xd+vbuf+pq16d+vtd per image
  int NB = 6;
  if (fixed + (size_t)NB * decPer + 4096 > ws_size) NB = 3;
  if (fixed + (size_t)NB * decPer + 4096 > ws_size) NB = 1;

  float* xd    = (float*)(wsb + fixed);
  float* vbuf  = xd + (size_t)NB * IMG_ELEMS;
  f16*   pq16d = (f16*)(vbuf + (size_t)NB * IMG_ELEMS);
  f16*   vtd   = pq16d + (size_t)NB * 991232ull;

  // ---- prep ----
  init_zero_kernel<<<dim3(1), dim3(1024), 0, stream>>>(ss);
  peT_kernel<<<dim3(512), dim3(256), 0, stream>>>(peT);
  build_labelT_kernel<<<dim3(48), dim3(256), 0, stream>>>(train_label, labT);
  cvt16_kernel<<<dim3(64), dim3(256), 0, stream>>>(wk_self, w16s);
  cvt16_kernel<<<dim3(64), dim3(256), 0, stream>>>(wk_cross, w16c);

  // ---- encoder ----
  build_input_kernel<<<dim3(16, 16, 48), dim3(32, 8), 0, stream>>>(
      train_feat, test_feat, peT, 0, xenc, vte, /*zmul=*/0, /*col_im_step=*/484, /*Lkp=*/1472);
  proj_mfma_kernel<<<dim3(363), dim3(256), 0, stream>>>(xenc, w16s, bk_self, (const float*)0, p16, LENC);
  attn3_kernel<0><<<dim3(23 * 16), dim3(512), 0, stream>>>(
      p16, p16, vte, (const float*)0, xenc, (float*)0, (const float*)0,
      ssE, (float*)0, (float*)0, LENC, LENC, 1472, 23, 0, 0);
  proj_mfma_kernel<<<dim3(363), dim3(256), 0, stream>>>(xenc, w16c, bk_cross, ssE, p16, LENC); // pkc
  v16t_mem_kernel<<<dim3(46, 16, 16), dim3(32, 8), 0, stream>>>(xenc, ssE, vtm);

  // ---- decoders (NB images per batch) ----
  for (int i0 = 0; i0 < 6; i0 += NB) {
    build_input_kernel<<<dim3(16, 16, NB * 16), dim3(32, 8), 0, stream>>>(
        train_feat, test_feat, peT, i0, xd, vtd, /*zmul=*/1, /*col_im_step=*/0, /*Lkp=*/512);
    // self-attention (+residual+ssA fused)
    proj_mfma_kernel<<<dim3(NB * 121), dim3(256), 0, stream>>>(xd, w16s, bk_self, (const float*)0, pq16d, HWSZ);
    attn3_kernel<0><<<dim3(8 * 16 * NB), dim3(512), 0, stream>>>(
        pq16d, pq16d, vtd, (const float*)0, xd, (float*)0, (const float*)0,
        ssA + i0 * 16, (float*)0, (float*)0, HWSZ, HWSZ, 512, 8, 0, 0);
    // cross-attention (mask/u/v/ssU/ssV/ssUV fused)
    proj_mfma_kernel<<<dim3(NB * 121), dim3(256), 0, stream>>>(xd, w16c, bk_cross, ssA + i0 * 16, pq16d, HWSZ);
    attn3_kernel<1><<<dim3(8 * 16 * NB), dim3(512), 0, stream>>>(
        pq16d, p16 /*pkc*/, vtm, labT, xd, vbuf, ssA + i0 * 16,
        ssU + i0 * 16, ssV + i0 * 16, ssUV + i0 * 16, HWSZ, LENC, 1472, 8, 1, 1);
    coef_final_kernel<<<dim3(1), dim3(128), 0, stream>>>(
        ssU + i0 * 16, ssV + i0 * 16, ssUV + i0 * 16, AB + i0 * 32, NB * 16);
    final_out_kernel<<<dim3(16, 16, NB * 16), dim3(32, 8), 0, stream>>>(
        xd, vbuf, AB + i0 * 32, out, i0);
  }
}